// Round 2
// baseline (349.509 us; speedup 1.0000x reference)
//
#include <hip/hip_runtime.h>
#include <math.h>

#define CC   16
#define HH   256
#define WW   256
#define HIDN 128
#define PDIM 144     // C*K*K
#define K1PAD 160    // GEMM1 K padded: 10 taps * 16 channels (tap 9 = zeros in W1T)
#define PITCH_H 136  // LDS pitch for h tile (halfs): 272B, 2-way banks on b128 reads
#define PP 2056      // gather LDS plane pitch in halfs (4112B: 16B-aligned, 4-bank stagger)

typedef _Float16 half8 __attribute__((ext_vector_type(8)));
typedef float   f32x4 __attribute__((ext_vector_type(4)));

#define MFMA16(a, b, c) __builtin_amdgcn_mfma_f32_16x16x32_f16((a), (b), (c), 0, 0, 0)

// ws layout
#define O_BYTES   ((size_t)524288 * 144 * 2)          // 150,994,944 (og: [b][a][tap][bcol][c] fp16)
#define W1T_OFF   O_BYTES                              // [n=128][k'=160] fp16, k' = tap*16 + c
#define W1T_BYTES ((size_t)128 * K1PAD * 2)            // 40,960
#define W2T_OFF   (W1T_OFF + W1T_BYTES)                // [nn=144][k=128] fp16, nn = tap*16 + c
#define W2T_BYTES ((size_t)144 * 128 * 2)              // 36,864
#define WS_NEEDED (W2T_OFF + W2T_BYTES)

__device__ __forceinline__ void load_lds16(const float* g, float* l)
{
#if __has_builtin(__builtin_amdgcn_global_load_lds)
    __builtin_amdgcn_global_load_lds(
        (const __attribute__((address_space(1))) unsigned int*)g,
        (__attribute__((address_space(3))) unsigned int*)l, 16, 0, 0);
#else
    *(float4*)l = *(const float4*)g;
#endif
}

__device__ __forceinline__ void load_lds16h(const _Float16* g, _Float16* l)
{
#if __has_builtin(__builtin_amdgcn_global_load_lds)
    __builtin_amdgcn_global_load_lds(
        (const __attribute__((address_space(1))) unsigned int*)g,
        (__attribute__((address_space(3))) unsigned int*)l, 16, 0, 0);
#else
    *(float4*)(void*)l = *(const float4*)(const void*)g;
#endif
}

// ---------------------------------------------------------------------------
// Prep: build fp16 transposed weights in d_ws (every launch; graph-safe).
// ---------------------------------------------------------------------------
__global__ __launch_bounds__(256) void prep_kernel(
    const float* __restrict__ W1, const float* __restrict__ W2,
    _Float16* __restrict__ W1T, _Float16* __restrict__ W2T)
{
    const int idx = blockIdx.x * 256 + threadIdx.x;
    if (idx < 128 * K1PAD) {
        const int n = idx / K1PAD;
        const int k = idx - n * K1PAD;
        const int tap = k >> 4;           // 0..9
        const int c   = k & 15;
        W1T[idx] = (tap < 9) ? (_Float16)W1[(c * 9 + tap) * HIDN + n] : (_Float16)0.f;
    }
    if (idx < 144 * 128) {
        const int nn = idx >> 7;          // 0..143
        const int k  = idx & 127;
        const int tap = nn >> 4;          // 0..8
        const int c   = nn & 15;
        W2T[nn * 128 + k] = (_Float16)W2[k * PDIM + (c * 9 + tap)];
    }
}

// ---------------------------------------------------------------------------
// Kernel A: coalesced async row staging -> in-LDS channel transpose ->
// fp16 MFMA MLP -> og in [b][a][tap][bcol][c] layout.
// 512 threads (8 waves) per block, one patch row a per block.
// LDS 73728B -> 2 blocks/CU -> 16 waves/CU (~50% occ).
// xT swizzle: s ^= (s & 0x1C0) >> 3  (folds xm bits 2..4 into bank bits ->
// both transpose b128 writes and GEMM1 A b128 reads are <=2-way).
// ---------------------------------------------------------------------------
__global__ __launch_bounds__(512) void mlp_kernel(
    const float* __restrict__ x,
    const _Float16* __restrict__ W1T, const float* __restrict__ b1,
    const _Float16* __restrict__ W2T, const float* __restrict__ b2,
    _Float16* __restrict__ og)
{
    __shared__ __align__(16) char smem[73728];
    _Float16* xT    = (_Float16*)smem;            // 24576 B (swizzled [i][xm][c] fp16)
    float*    xrowF = (float*)(smem + 24576);     // 49152 B ([i][c][xm] f32, dead after 0b)
    _Float16* hT    = (_Float16*)(smem + 24576);  // 34816 B (overlaps xrowF)

    const int tid   = threadIdx.x;
    const int a     = blockIdx.x & 127;   // patch row
    const int batch = blockIdx.x >> 7;
    const float* xb = x + (size_t)batch * CC * HH * WW;

    // ---- 0a: stage 3 x-rows (ym = 2a-1..2a+1, reflect) as f32 [i][c][xm].
    #pragma unroll
    for (int it = 0; it < 6; ++it) {
        const int idx = tid + it * 512;   // 0..3071
        const int i   = idx >> 10;        // 0..2
        const int c   = (idx >> 6) & 15;
        const int q   = idx & 63;
        int ym = 2 * a + i - 1;
        if (ym < 0) ym = 1;               // reflect top edge
        load_lds16(xb + ((c * HH + ym) * WW + 4 * q), xrowF + idx * 4);
    }
    __syncthreads();

    // ---- 0b: transpose to xT[i][xm][c] fp16 with 3-bit bank swizzle.
    #pragma unroll
    for (int k = 0; k < 2; ++k) {
        const int u = tid + k * 512;      // u = i*256 + xm, 0..767
        if (u < 768) {
            const int i  = u >> 8;
            const int xm = u & 255;
            const float* rbase = xrowF + i * 4096 + xm;
            half8 lo, hi;
            #pragma unroll
            for (int c = 0; c < 8; ++c) lo[c] = (_Float16)rbase[c * 256];
            #pragma unroll
            for (int c = 0; c < 8; ++c) hi[c] = (_Float16)rbase[(c + 8) * 256];
            int s = u << 4;               // (i*256+xm)*16 halfs
            s ^= (s & 0x1C0) >> 3;        // bits 3..5 ^= bits 6..8
            *(half8*)(xT + s)       = lo;
            *(half8*)(xT + (s ^ 8)) = hi;
        }
    }
    __syncthreads();

    const int wid  = tid >> 6;            // 0..7
    const int lane = tid & 63;
    const int l15  = lane & 15;
    const int quad = lane >> 4;
    const int qh   = quad >> 1;
    const int c0   = (quad & 1) * 8;
    const int wm   = wid >> 2;            // mt half: 0 -> mt 0..3, 1 -> mt 4..7
    const int wn   = wid & 3;             // nt pair {2wn, 2wn+1}

    // ---- GEMM1: h = relu(patches @ W1 + b1).  M=128, N=128, K=160 (tap-major).
    {
        half8 bfr0[5], bfr1[5];
        float bias0, bias1;
        {
            const int nt0 = 2 * wn, nt1 = 2 * wn + 1;
            const _Float16* w0 = W1T + (nt0 * 16 + l15) * K1PAD + quad * 8;
            const _Float16* w1 = W1T + (nt1 * 16 + l15) * K1PAD + quad * 8;
            #pragma unroll
            for (int ks = 0; ks < 5; ++ks) {
                bfr0[ks] = *(const half8*)(w0 + ks * 32);
                bfr1[ks] = *(const half8*)(w1 + ks * 32);
            }
            bias0 = b1[nt0 * 16 + l15];
            bias1 = b1[nt1 * 16 + l15];
        }
        // Per-ks A offsets (linear, pre-swizzle): kbase = ks*32 + quad*8 ->
        // tap = 2ks+qh, channel-half c0.  tap 9 clamped to 8 (W1T zero there).
        int koffU[5], koffF[5];
        #pragma unroll
        for (int ks = 0; ks < 5; ++ks) {
            int tap = 2 * ks + qh;
            if (tap > 8) tap = 8;
            const int i   = (tap * 11) >> 5;   // tap/3
            const int j   = tap - 3 * i;
            const int xmU = 2 * l15 + j - 1;
            const int xmF = (xmU < 0) ? 1 : xmU;   // reflect left edge (mt=0 only)
            koffU[ks] = (i << 12) + (xmU << 4) + c0;
            koffF[ks] = (i << 12) + (xmF << 4) + c0;
        }

        #define G1_STEP(MT, KO)                                                   \
        {                                                                         \
            f32x4 acc0 = {0.f, 0.f, 0.f, 0.f};                                    \
            f32x4 acc1 = {0.f, 0.f, 0.f, 0.f};                                    \
            _Pragma("unroll")                                                     \
            for (int ks = 0; ks < 5; ++ks) {                                      \
                int ix = KO[ks] + ((MT) << 9);                                    \
                ix ^= (ix & 0x1C0) >> 3;                                          \
                const half8 af = *(const half8*)(xT + ix);                        \
                acc0 = MFMA16(af, bfr0[ks], acc0);                                \
                acc1 = MFMA16(af, bfr1[ks], acc1);                                \
            }                                                                     \
            _Pragma("unroll")                                                     \
            for (int r = 0; r < 4; ++r) {                                         \
                const int row = (MT) * 16 + quad * 4 + r;                         \
                float h0 = acc0[r] + bias0;                                       \
                float h1 = acc1[r] + bias1;                                       \
                hT[row * PITCH_H + (2 * wn) * 16 + l15]     = (_Float16)(h0 > 0.f ? h0 : 0.f); \
                hT[row * PITCH_H + (2 * wn + 1) * 16 + l15] = (_Float16)(h1 > 0.f ? h1 : 0.f); \
            }                                                                     \
        }

        if (wm == 0) {
            G1_STEP(0, koffF)
            #pragma unroll
            for (int mt = 1; mt < 4; ++mt) G1_STEP(mt, koffU)
        } else {
            #pragma unroll
            for (int mt = 4; mt < 8; ++mt) G1_STEP(mt, koffU)
        }
        #undef G1_STEP
    }
    __syncthreads();

    // ---- GEMM2: o = h @ W2perm + b2perm.  M=128, N=144, K=128.
    // og layout: [batch][a][tap][bcol][c] fp16.
    const size_t abase = ((size_t)batch * 128 + a) * 9;
    {
        // main: nt pair {2wn, 2wn+1}, mt in [wm*4, wm*4+4)
        half8 bfr2[2][4];
        float bias2[2];
        #pragma unroll
        for (int n = 0; n < 2; ++n) {
            const int nt = 2 * wn + n;
            const _Float16* w2row = W2T + (nt * 16 + l15) * 128 + quad * 8;
            #pragma unroll
            for (int ks = 0; ks < 4; ++ks)
                bfr2[n][ks] = *(const half8*)(w2row + ks * 32);
            bias2[n] = b2[l15 * 9 + nt];
        }
        _Float16* ognA = og + (abase + 2 * wn) * 2048;
        _Float16* ognB = og + (abase + 2 * wn + 1) * 2048;
        #pragma unroll
        for (int m = 0; m < 4; ++m) {
            const int mt = wm * 4 + m;
            f32x4 acc0 = {0.f, 0.f, 0.f, 0.f};
            f32x4 acc1 = {0.f, 0.f, 0.f, 0.f};
            const _Float16* arow = hT + (mt * 16 + l15) * PITCH_H + quad * 8;
            #pragma unroll
            for (int ks = 0; ks < 4; ++ks) {
                const half8 af = *(const half8*)(arow + ks * 32);
                acc0 = MFMA16(af, bfr2[0][ks], acc0);
                acc1 = MFMA16(af, bfr2[1][ks], acc1);
            }
            #pragma unroll
            for (int r = 0; r < 4; ++r) {
                const int b = mt * 16 + quad * 4 + r;
                ognA[b * 16 + l15] = (_Float16)(acc0[r] + bias2[0]);
                ognB[b * 16 + l15] = (_Float16)(acc1[r] + bias2[1]);
            }
        }
        // tail: nt = 8, wave w handles mt = w (balanced)
        {
            half8 bfr8[4];
            const _Float16* w2row = W2T + (8 * 16 + l15) * 128 + quad * 8;
            #pragma unroll
            for (int ks = 0; ks < 4; ++ks)
                bfr8[ks] = *(const half8*)(w2row + ks * 32);
            const float bias8 = b2[l15 * 9 + 8];
            _Float16* ogn = og + (abase + 8) * 2048;
            const int mt = wid;
            f32x4 acc = {0.f, 0.f, 0.f, 0.f};
            const _Float16* arow = hT + (mt * 16 + l15) * PITCH_H + quad * 8;
            #pragma unroll
            for (int ks = 0; ks < 4; ++ks)
                acc = MFMA16(*(const half8*)(arow + ks * 32), bfr8[ks], acc);
            #pragma unroll
            for (int r = 0; r < 4; ++r) {
                const int b = mt * 16 + quad * 4 + r;
                ogn[b * 16 + l15] = (_Float16)(acc[r] + bias8);
            }
        }
    }
}

// ---------------------------------------------------------------------------
// Kernel B: LDS-staged gather-fold + analytic-count normalize + 16x16
// channel mix + softmax + modulate. One block per (batch, output row y).
// Stage <=6 contiguous 4KB og tap-planes via global_load_lds (coalesced,
// uniform), then do the divergent 32B per-pixel gathers from LDS.
// ---------------------------------------------------------------------------
__global__ __launch_bounds__(256) void gather_kernel(
    const _Float16* __restrict__ og, const float* __restrict__ Wc,
    const float* __restrict__ bc, float* __restrict__ out)
{
    __shared__ __align__(16) _Float16 sPl[6 * PP];   // 24672 B
    __shared__ float sWc[256];
    __shared__ float sbc[16];

    const int tid   = threadIdx.x;
    const int y     = blockIdx.x & 255;
    const int batch = blockIdx.x >> 8;

    sWc[tid] = Wc[tid];
    if (tid < 16) sbc[tid] = bc[tid];

    // contributing patch rows (a, i): ypad = y+1 = 2a + i  (uniform over block)
    int alist[2], ilist[2], na = 0;
    if ((y + 1) & 1) { alist[0] = y >> 1; ilist[0] = 1; na = 1; }
    else {
        if (y < 255) { alist[na] = (y + 1) >> 1; ilist[na] = 0; ++na; }
        alist[na] = (y - 1) >> 1; ilist[na] = 2; ++na;
    }

    // stage na*3 planes (each 4096B = 256 x 16B chunks)
    const size_t pb = (size_t)batch * 128;
    for (int p = 0; p < na * 3; ++p) {
        const int u   = (p >= 3) ? 1 : 0;
        const int j   = p - 3 * u;
        const int tap = ilist[u] * 3 + j;
        const _Float16* src = og + ((pb + alist[u]) * 9 + tap) * 2048 + tid * 8;
        load_lds16h(src, sPl + p * PP + tid * 8);
    }
    __syncthreads();

    const int x = tid;
    int blist[2], jlist[2], nb = 0;
    if ((x + 1) & 1) { blist[0] = x >> 1; jlist[0] = 1; nb = 1; }
    else {
        if (x < 255) { blist[nb] = (x + 1) >> 1; jlist[nb] = 0; ++nb; }
        blist[nb] = (x - 1) >> 1; jlist[nb] = 2; ++nb;
    }

    float nrm[CC];
    #pragma unroll
    for (int c = 0; c < CC; ++c) nrm[c] = 0.f;

    for (int u = 0; u < 2; ++u) {
        if (u >= na) break;
        for (int v = 0; v < 2; ++v) {
            if (v >= nb) break;
            const _Float16* orow = sPl + (u * 3 + jlist[v]) * PP + blist[v] * 16;
            const half8 o0 = *(const half8*)(orow);
            const half8 o1 = *(const half8*)(orow + 8);
            #pragma unroll
            for (int e = 0; e < 8; ++e) { nrm[e] += (float)o0[e]; nrm[8 + e] += (float)o1[e]; }
        }
    }
    const float inv = 1.f / ((float)(na * nb) + 1e-6f);
    #pragma unroll
    for (int c = 0; c < CC; ++c) nrm[c] *= inv;

    float lg[CC];
    #pragma unroll
    for (int o = 0; o < CC; ++o) {
        float s = sbc[o];
        #pragma unroll
        for (int c = 0; c < CC; ++c) s = fmaf(sWc[o * CC + c], nrm[c], s);
        lg[o] = s;
    }
    float mx = lg[0];
    #pragma unroll
    for (int o = 1; o < CC; ++o) mx = fmaxf(mx, lg[o]);
    float se = 0.f;
    #pragma unroll
    for (int o = 0; o < CC; ++o) { lg[o] = expf(lg[o] - mx); se += lg[o]; }
    const float isum = 1.f / se;

    const size_t obase = ((size_t)batch * CC) * (HH * WW) + (size_t)y * WW + x;
    #pragma unroll
    for (int c = 0; c < CC; ++c)
        out[obase + (size_t)c * (HH * WW)] = nrm[c] * lg[c] * isum;
}

// ===========================================================================
// FALLBACK (round-1 path) — used only if ws_size is too small.
// ===========================================================================
#define HT_PITCH 68
__global__ __launch_bounds__(256) void mlp_fold_kernel_fb(
    const float* __restrict__ x,  const float* __restrict__ W1,
    const float* __restrict__ b1, const float* __restrict__ W2,
    const float* __restrict__ b2, float* __restrict__ folded)
{
    __shared__ __align__(16) float pT[PDIM * 64];
    __shared__ __align__(16) float hT[HIDN * HT_PITCH];
    const int tid = threadIdx.x;
    const int tile = blockIdx.x & 255;
    const int b = blockIdx.x >> 8;
    const int tile_base = tile * 64;
    const float* xb = x + (size_t)b * CC * HH * WW;
    for (int idx = tid; idx < PDIM * 64; idx += 256) {
        const int p = idx >> 6, lo = idx & 63;
        const int c = p / 9, rem = p - c * 9, i = rem / 3, j = rem - i * 3;
        const int l = tile_base + lo, a = l >> 7, bb = l & 127;
        int ym = 2 * a + i - 1, xm = 2 * bb + j - 1;
        if (ym < 0) ym = 1;
        if (xm < 0) xm = 1;
        pT[p * 64 + lo] = xb[(c * HH + ym) * WW + xm];
    }
    __syncthreads();
    {
        const int cg = tid & 31, rg = tid >> 5, rbase = rg * 8;
        float acc[8][4];
        #pragma unroll
        for (int m = 0; m < 8; ++m)
            #pragma unroll
            for (int jj = 0; jj < 4; ++jj) acc[m][jj] = 0.f;
        for (int k = 0; k < PDIM; ++k) {
            const float4 w = *reinterpret_cast<const float4*>(W1 + k * HIDN + cg * 4);
            const float4 pa = *reinterpret_cast<const float4*>(pT + k * 64 + rbase);
            const float4 pb2 = *reinterpret_cast<const float4*>(pT + k * 64 + rbase + 4);
            const float pv[8] = {pa.x, pa.y, pa.z, pa.w, pb2.x, pb2.y, pb2.z, pb2.w};
            const float wv[4] = {w.x, w.y, w.z, w.w};
            #pragma unroll
            for (int m = 0; m < 8; ++m)
                #pragma unroll
                for (int jj = 0; jj < 4; ++jj) acc[m][jj] = fmaf(pv[m], wv[jj], acc[m][jj]);
        }
        #pragma unroll
        for (int jj = 0; jj < 4; ++jj) {
            const int jcol = cg * 4 + jj;
            const float bj = b1[jcol];
            #pragma unroll
            for (int m = 0; m < 8; ++m) {
                const float hval = acc[m][jj] + bj;
                hT[jcol * HT_PITCH + rbase + m] = hval > 0.f ? hval : 0.f;
            }
        }
    }
    __syncthreads();
    {
        const int cg2 = tid & 15, rg2 = tid >> 4, rb2 = rg2 * 4;
        float acc2[4][9];
        #pragma unroll
        for (int m = 0; m < 4; ++m)
            #pragma unroll
            for (int jj = 0; jj < 9; ++jj) acc2[m][jj] = 0.f;
        const float* w2base = W2 + cg2 * 9;
        for (int h = 0; h < HIDN; ++h) {
            const float4 hv4 = *reinterpret_cast<const float4*>(hT + h * HT_PITCH + rb2);
            const float hv[4] = {hv4.x, hv4.y, hv4.z, hv4.w};
            float wv[9];
            #pragma unroll
            for (int jj = 0; jj < 9; ++jj) wv[jj] = w2base[h * PDIM + jj];
            #pragma unroll
            for (int m = 0; m < 4; ++m)
                #pragma unroll
                for (int jj = 0; jj < 9; ++jj) acc2[m][jj] = fmaf(hv[m], wv[jj], acc2[m][jj]);
        }
        float bv[9];
        #pragma unroll
        for (int jj = 0; jj < 9; ++jj) bv[jj] = b2[cg2 * 9 + jj];
        float* fb = folded + ((size_t)b * CC + cg2) * (HH * WW);
        #pragma unroll
        for (int m = 0; m < 4; ++m) {
            const int l = tile_base + rb2 + m, a = l >> 7, bb = l & 127;
            #pragma unroll
            for (int jj = 0; jj < 9; ++jj) {
                const int i = jj / 3, j2 = jj - i * 3;
                const int ypad = 2 * a + i, xpad = 2 * bb + j2;
                if (ypad >= 1 && xpad >= 1)
                    atomicAdd(fb + (ypad - 1) * WW + (xpad - 1), acc2[m][jj] + bv[jj]);
            }
        }
    }
}

__global__ __launch_bounds__(256) void norm_softmax_kernel_fb(
    float* __restrict__ out, const float* __restrict__ Wc, const float* __restrict__ bc)
{
    const int xo = threadIdx.x, yo = blockIdx.x & 255, b = blockIdx.x >> 8;
    const int yp = yo + 1, xp = xo + 1;
    const float cy = ((yp & 1) || yp == 256) ? 1.f : 2.f;
    const float cx = ((xp & 1) || xp == 256) ? 1.f : 2.f;
    const float inv = 1.f / (cy * cx + 1e-6f);
    const size_t base = ((size_t)b * CC) * (HH * WW) + (size_t)yo * WW + xo;
    float nrm[CC];
    #pragma unroll
    for (int c = 0; c < CC; ++c) nrm[c] = out[base + (size_t)c * (HH * WW)] * inv;
    float logits[CC];
    #pragma unroll
    for (int o = 0; o < CC; ++o) {
        float s = bc[o];
        #pragma unroll
        for (int c = 0; c < CC; ++c) s = fmaf(Wc[o * CC + c], nrm[c], s);
        logits[o] = s;
    }
    float mx = logits[0];
    #pragma unroll
    for (int o = 1; o < CC; ++o) mx = fmaxf(mx, logits[o]);
    float se = 0.f;
    #pragma unroll
    for (int o = 0; o < CC; ++o) { logits[o] = expf(logits[o] - mx); se += logits[o]; }
    const float isum = 1.f / se;
    #pragma unroll
    for (int c = 0; c < CC; ++c)
        out[base + (size_t)c * (HH * WW)] = nrm[c] * logits[c] * isum;
}

// ---------------------------------------------------------------------------
extern "C" void kernel_launch(void* const* d_in, const int* in_sizes, int n_in,
                              void* d_out, int out_size, void* d_ws, size_t ws_size,
                              hipStream_t stream)
{
    const float* x  = (const float*)d_in[0];
    const float* W1 = (const float*)d_in[1];
    const float* b1 = (const float*)d_in[2];
    const float* W2 = (const float*)d_in[3];
    const float* b2 = (const float*)d_in[4];
    const float* Wc = (const float*)d_in[5];
    const float* bc = (const float*)d_in[6];
    float* out = (float*)d_out;

    if (ws_size >= WS_NEEDED) {
        _Float16* og  = (_Float16*)d_ws;
        _Float16* W1T = (_Float16*)((char*)d_ws + W1T_OFF);
        _Float16* W2T = (_Float16*)((char*)d_ws + W2T_OFF);

        prep_kernel<<<dim3(80), dim3(256), 0, stream>>>(W1, W2, W1T, W2T);
        // 32 batches x 128 patch rows, 512 threads (8 waves)
        mlp_kernel<<<dim3(32 * 128), dim3(512), 0, stream>>>(x, W1T, b1, W2T, b2, og);
        // 32 batches x 256 output rows
        gather_kernel<<<dim3(32 * 256), dim3(256), 0, stream>>>(og, Wc, bc, out);
    } else {
        hipMemsetAsync(d_out, 0, (size_t)out_size * sizeof(float), stream);
        mlp_fold_kernel_fb<<<dim3(32 * 256), dim3(256), 0, stream>>>(x, W1, b1, W2, b2, out);
        norm_softmax_kernel_fb<<<dim3(32 * 256), dim3(256), 0, stream>>>(out, Wc, bc);
    }
}

// Round 3
// 332.198 us; speedup vs baseline: 1.0521x; 1.0521x over previous
//
#include <hip/hip_runtime.h>
#include <math.h>

#define CC   16
#define HH   256
#define WW   256
#define HIDN 128
#define PDIM 144     // C*K*K
#define K1PAD 160    // GEMM1 K padded: 10 taps * 16 channels (tap 9 = zeros in W1T)
#define PITCH_H 136  // LDS pitch for h tile (halfs): 272B, 2-way banks on b128 reads

typedef _Float16 half8 __attribute__((ext_vector_type(8)));
typedef float   f32x4 __attribute__((ext_vector_type(4)));

#define MFMA16(a, b, c) __builtin_amdgcn_mfma_f32_16x16x32_f16((a), (b), (c), 0, 0, 0)

// ws layout
#define O_BYTES   ((size_t)524288 * 144 * 2)          // 150,994,944 (og: [b][a][tap][bcol][c] fp16)
#define W1T_OFF   O_BYTES                              // [n=128][k'=160] fp16, k' = tap*16 + c
#define W1T_BYTES ((size_t)128 * K1PAD * 2)            // 40,960
#define W2T_OFF   (W1T_OFF + W1T_BYTES)                // [nn=144][k=128] fp16, nn = tap*16 + c
#define W2T_BYTES ((size_t)144 * 128 * 2)              // 36,864
#define WS_NEEDED (W2T_OFF + W2T_BYTES)

__device__ __forceinline__ void load_lds16(const float* g, float* l)
{
#if __has_builtin(__builtin_amdgcn_global_load_lds)
    __builtin_amdgcn_global_load_lds(
        (const __attribute__((address_space(1))) unsigned int*)g,
        (__attribute__((address_space(3))) unsigned int*)l, 16, 0, 0);
#else
    *(float4*)l = *(const float4*)g;
#endif
}

__device__ __forceinline__ void load_lds16h(const _Float16* g, _Float16* l)
{
#if __has_builtin(__builtin_amdgcn_global_load_lds)
    __builtin_amdgcn_global_load_lds(
        (const __attribute__((address_space(1))) unsigned int*)g,
        (__attribute__((address_space(3))) unsigned int*)l, 16, 0, 0);
#else
    *(float4*)(void*)l = *(const float4*)(const void*)g;
#endif
}

// ---------------------------------------------------------------------------
// Prep: build fp16 transposed weights in d_ws (every launch; graph-safe).
// ---------------------------------------------------------------------------
__global__ __launch_bounds__(256) void prep_kernel(
    const float* __restrict__ W1, const float* __restrict__ W2,
    _Float16* __restrict__ W1T, _Float16* __restrict__ W2T)
{
    const int idx = blockIdx.x * 256 + threadIdx.x;
    if (idx < 128 * K1PAD) {
        const int n = idx / K1PAD;
        const int k = idx - n * K1PAD;
        const int tap = k >> 4;           // 0..9
        const int c   = k & 15;
        W1T[idx] = (tap < 9) ? (_Float16)W1[(c * 9 + tap) * HIDN + n] : (_Float16)0.f;
    }
    if (idx < 144 * 128) {
        const int nn = idx >> 7;          // 0..143
        const int k  = idx & 127;
        const int tap = nn >> 4;          // 0..8
        const int c   = nn & 15;
        W2T[nn * 128 + k] = (_Float16)W2[k * PDIM + (c * 9 + tap)];
    }
}

// ---------------------------------------------------------------------------
// Kernel A (round-1 structure, 256 thr / 4 waves / VGPR~108):
// coalesced async row staging -> in-LDS channel transpose -> fp16 MFMA MLP
// -> og in [b][a][tap][bcol][c] layout.  One block = one patch row a.
// GEMM2 change vs round-1: wave w owns nt {w, w+4} sharing each hT A-read
// across 2 MFMAs + balanced nt=8 tail (hT b128 reads 288 -> 160 per block).
// ---------------------------------------------------------------------------
__global__ __launch_bounds__(256) void mlp_kernel(
    const float* __restrict__ x,
    const _Float16* __restrict__ W1T, const float* __restrict__ b1,
    const _Float16* __restrict__ W2T, const float* __restrict__ b2,
    _Float16* __restrict__ og)
{
    __shared__ __align__(16) char smem[73728];
    _Float16* xT    = (_Float16*)smem;            // 24576 B (swizzled [i][xm][c] fp16)
    float*    xrowF = (float*)(smem + 24576);     // 49152 B ([i][c][xm] f32, dead after 0b)
    _Float16* hT    = (_Float16*)(smem + 24576);  // 34816 B (overlaps xrowF)

    const int tid   = threadIdx.x;
    const int a     = blockIdx.x & 127;   // patch row
    const int batch = blockIdx.x >> 7;
    const float* xb = x + (size_t)batch * CC * HH * WW;

    // ---- 0a: stage 3 x-rows (ym = 2a-1..2a+1, reflect) as f32 [i][c][xm].
    #pragma unroll
    for (int it = 0; it < 12; ++it) {
        const int idx = tid + it * 256;   // 0..3071
        const int i   = idx >> 10;        // 0..2
        const int c   = (idx >> 6) & 15;
        const int q   = idx & 63;
        int ym = 2 * a + i - 1;
        if (ym < 0) ym = 1;               // reflect top edge
        load_lds16(xb + ((c * HH + ym) * WW + 4 * q), xrowF + idx * 4);
    }
    __syncthreads();

    // ---- 0b: transpose to xT[i][xm][c] fp16 with 3-bit bank swizzle.
    #pragma unroll
    for (int k = 0; k < 3; ++k) {
        const int u  = tid + k * 256;     // u = i*256 + xm
        const int i  = u >> 8;
        const int xm = u & 255;
        const float* rbase = xrowF + i * 4096 + xm;
        half8 lo, hi;
        #pragma unroll
        for (int c = 0; c < 8; ++c) lo[c] = (_Float16)rbase[c * 256];
        #pragma unroll
        for (int c = 0; c < 8; ++c) hi[c] = (_Float16)rbase[(c + 8) * 256];
        int s = u << 4;                   // (i*256+xm)*16 halfs
        s ^= (s & 0x1C0) >> 3;            // bits 3..5 ^= bits 6..8
        *(half8*)(xT + s)       = lo;
        *(half8*)(xT + (s ^ 8)) = hi;
    }
    __syncthreads();

    const int wid  = tid >> 6;            // 0..3
    const int lane = tid & 63;
    const int l15  = lane & 15;
    const int quad = lane >> 4;
    const int qh   = quad >> 1;
    const int c0   = (quad & 1) * 8;

    // ---- GEMM1: h = relu(patches @ W1 + b1).  M=128, N=128, K=160 (tap-major).
    {
        half8 bfr0[5], bfr1[5];
        float bias0, bias1;
        {
            const int nt0 = 2 * wid, nt1 = 2 * wid + 1;
            const _Float16* w0 = W1T + (nt0 * 16 + l15) * K1PAD + quad * 8;
            const _Float16* w1 = W1T + (nt1 * 16 + l15) * K1PAD + quad * 8;
            #pragma unroll
            for (int ks = 0; ks < 5; ++ks) {
                bfr0[ks] = *(const half8*)(w0 + ks * 32);
                bfr1[ks] = *(const half8*)(w1 + ks * 32);
            }
            bias0 = b1[nt0 * 16 + l15];
            bias1 = b1[nt1 * 16 + l15];
        }
        // Per-ks A offsets (linear, pre-swizzle): kbase = ks*32 + quad*8 ->
        // tap = 2ks+qh, channel-half c0.  tap 9 clamped to 8 (W1T zero there).
        int koffU[5], koffF[5];
        #pragma unroll
        for (int ks = 0; ks < 5; ++ks) {
            int tap = 2 * ks + qh;
            if (tap > 8) tap = 8;
            const int i   = (tap * 11) >> 5;   // tap/3
            const int j   = tap - 3 * i;
            const int xmU = 2 * l15 + j - 1;
            const int xmF = (xmU < 0) ? 1 : xmU;   // reflect left edge (mt=0 only)
            koffU[ks] = (i << 12) + (xmU << 4) + c0;
            koffF[ks] = (i << 12) + (xmF << 4) + c0;
        }

        #define G1_STEP(MT, KO)                                                   \
        {                                                                         \
            f32x4 acc0 = {0.f, 0.f, 0.f, 0.f};                                    \
            f32x4 acc1 = {0.f, 0.f, 0.f, 0.f};                                    \
            _Pragma("unroll")                                                     \
            for (int ks = 0; ks < 5; ++ks) {                                      \
                int ix = KO[ks] + ((MT) << 9);                                    \
                ix ^= (ix & 0x1C0) >> 3;                                          \
                const half8 af = *(const half8*)(xT + ix);                        \
                acc0 = MFMA16(af, bfr0[ks], acc0);                                \
                acc1 = MFMA16(af, bfr1[ks], acc1);                                \
            }                                                                     \
            _Pragma("unroll")                                                     \
            for (int r = 0; r < 4; ++r) {                                         \
                const int row = (MT) * 16 + quad * 4 + r;                         \
                float h0 = acc0[r] + bias0;                                       \
                float h1 = acc1[r] + bias1;                                       \
                hT[row * PITCH_H + (2 * wid) * 16 + l15]     = (_Float16)(h0 > 0.f ? h0 : 0.f); \
                hT[row * PITCH_H + (2 * wid + 1) * 16 + l15] = (_Float16)(h1 > 0.f ? h1 : 0.f); \
            }                                                                     \
        }

        G1_STEP(0, koffF)
        for (int mt = 1; mt < 8; ++mt) G1_STEP(mt, koffU)
        #undef G1_STEP
    }
    __syncthreads();

    // ---- GEMM2: o = h @ W2perm + b2perm.  M=128, N=144, K=128.
    // og layout: [batch][a][tap][bcol][c] fp16 (2048 halfs per tap plane).
    const size_t abase = ((size_t)batch * 128 + a) * 9;
    {
        // main: nt pair {wid, wid+4}; one hT A-read feeds 2 MFMAs
        half8 bfr2[2][4];
        float bias2[2];
        #pragma unroll
        for (int n = 0; n < 2; ++n) {
            const int nt = wid + n * 4;
            const _Float16* w2row = W2T + (nt * 16 + l15) * 128 + quad * 8;
            #pragma unroll
            for (int ks = 0; ks < 4; ++ks)
                bfr2[n][ks] = *(const half8*)(w2row + ks * 32);
            bias2[n] = b2[l15 * 9 + nt];
        }
        _Float16* ognA = og + (abase + wid) * 2048;
        _Float16* ognB = og + (abase + wid + 4) * 2048;
        for (int mt = 0; mt < 8; ++mt) {
            f32x4 acc0 = {0.f, 0.f, 0.f, 0.f};
            f32x4 acc1 = {0.f, 0.f, 0.f, 0.f};
            const _Float16* arow = hT + (mt * 16 + l15) * PITCH_H + quad * 8;
            #pragma unroll
            for (int ks = 0; ks < 4; ++ks) {
                const half8 af = *(const half8*)(arow + ks * 32);
                acc0 = MFMA16(af, bfr2[0][ks], acc0);
                acc1 = MFMA16(af, bfr2[1][ks], acc1);
            }
            #pragma unroll
            for (int r = 0; r < 4; ++r) {
                const int b = mt * 16 + quad * 4 + r;
                ognA[b * 16 + l15] = (_Float16)(acc0[r] + bias2[0]);
                ognB[b * 16 + l15] = (_Float16)(acc1[r] + bias2[1]);
            }
        }
        // tail: nt = 8, wave w handles mt {2w, 2w+1} (balanced)
        {
            half8 bfr8[4];
            const _Float16* w2row = W2T + (8 * 16 + l15) * 128 + quad * 8;
            #pragma unroll
            for (int ks = 0; ks < 4; ++ks)
                bfr8[ks] = *(const half8*)(w2row + ks * 32);
            const float bias8 = b2[l15 * 9 + 8];
            _Float16* ogn = og + (abase + 8) * 2048;
            #pragma unroll
            for (int m = 0; m < 2; ++m) {
                const int mt = 2 * wid + m;
                f32x4 acc = {0.f, 0.f, 0.f, 0.f};
                const _Float16* arow = hT + (mt * 16 + l15) * PITCH_H + quad * 8;
                #pragma unroll
                for (int ks = 0; ks < 4; ++ks)
                    acc = MFMA16(*(const half8*)(arow + ks * 32), bfr8[ks], acc);
                #pragma unroll
                for (int r = 0; r < 4; ++r) {
                    const int b = mt * 16 + quad * 4 + r;
                    ogn[b * 16 + l15] = (_Float16)(acc[r] + bias8);
                }
            }
        }
    }
}

// ---------------------------------------------------------------------------
// Kernel B: one block per (batch, patch row a) = output rows y0=2a, y1=2a+1.
// The row pair shares patch-row a's planes: stage 9 planes once (og read
// exactly once overall), XOR-swizzled so the per-pixel 16B gathers are
// bank-conflict-free.  global_load_lds writes linearly -> swizzle applied
// to the per-lane GLOBAL source chunk (involution), swizzle on read addrs.
//   planes 0..2: (a,   taps 3..5)  -> even row (i=1)
//   planes 3..5: (a,   taps 6..8)  -> odd  row (i=2)
//   planes 6..8: (a+1, taps 0..2)  -> odd  row (i=0), absent when a==127
// ---------------------------------------------------------------------------
__global__ __launch_bounds__(256) void gather_kernel(
    const _Float16* __restrict__ og, const float* __restrict__ Wc,
    const float* __restrict__ bc, float* __restrict__ out)
{
    __shared__ __align__(16) _Float16 sPl[9 * 2048];   // 36864 B
    __shared__ float sWc[256];
    __shared__ float sbc[16];

    const int tid   = threadIdx.x;
    const int a     = blockIdx.x & 127;
    const int batch = blockIdx.x >> 7;

    sWc[tid] = Wc[tid];
    if (tid < 16) sbc[tid] = bc[tid];

    const size_t pb = (size_t)batch * 128;
    const int a1 = (a < 127) ? a + 1 : 127;          // clamped; data unused if a==127
    const int srcOff = (tid ^ ((tid >> 3) & 7)) * 8; // inverse-swizzled source chunk
    #pragma unroll
    for (int p = 0; p < 9; ++p) {
        const int ap  = (p < 6) ? a : a1;
        const int tap = (p < 3) ? (3 + p) : ((p < 6) ? (3 + p) : (p - 6));
        const _Float16* src = og + ((pb + ap) * 9 + tap) * 2048 + srcOff;
        load_lds16h(src, sPl + p * 2048 + tid * 8);
    }
    __syncthreads();

    const int x = tid;
    int blist[2], jlist[2], nb = 0;
    if ((x + 1) & 1) { blist[0] = x >> 1; jlist[0] = 1; nb = 1; }
    else {
        if (x < 255) { blist[nb] = (x + 1) >> 1; jlist[nb] = 0; ++nb; }
        blist[nb] = (x - 1) >> 1; jlist[nb] = 2; ++nb;
    }
    const int na1 = (a < 127) ? 2 : 1;   // odd row vertical contributors

    float nrm0[CC], nrm1[CC];
    #pragma unroll
    for (int c = 0; c < CC; ++c) { nrm0[c] = 0.f; nrm1[c] = 0.f; }

    #define ACC_PLANE(P, B, DST)                                             \
    {                                                                        \
        int s = (B) * 16;                                                    \
        s ^= (s & 0x1C0) >> 3;                                               \
        const _Float16* orow = sPl + (P) * 2048;                             \
        const half8 o0 = *(const half8*)(orow + s);                          \
        const half8 o1 = *(const half8*)(orow + (s ^ 8));                    \
        _Pragma("unroll")                                                    \
        for (int e = 0; e < 8; ++e) { DST[e] += (float)o0[e]; DST[8 + e] += (float)o1[e]; } \
    }

    for (int v = 0; v < 2; ++v) {
        if (v >= nb) break;
        const int j = jlist[v];
        const int b = blist[v];
        ACC_PLANE(j,     b, nrm0)        // even row, i=1 (taps 3..5)
        ACC_PLANE(3 + j, b, nrm1)        // odd row,  i=2 (taps 6..8)
        if (na1 == 2) ACC_PLANE(6 + j, b, nrm1)  // odd row, i=0 (taps 0..2)
    }
    #undef ACC_PLANE

    const float inv0 = 1.f / ((float)nb + 1e-6f);
    const float inv1 = 1.f / ((float)(na1 * nb) + 1e-6f);
    #pragma unroll
    for (int c = 0; c < CC; ++c) { nrm0[c] *= inv0; nrm1[c] *= inv1; }

    // channel mix + softmax + modulate, both rows
    const size_t obase = ((size_t)batch * CC) * (HH * WW) + (size_t)(2 * a) * WW + x;
    #pragma unroll
    for (int rowsel = 0; rowsel < 2; ++rowsel) {
        const float* nrm = rowsel ? nrm1 : nrm0;
        float lg[CC];
        #pragma unroll
        for (int o = 0; o < CC; ++o) {
            float s = sbc[o];
            #pragma unroll
            for (int c = 0; c < CC; ++c) s = fmaf(sWc[o * CC + c], nrm[c], s);
            lg[o] = s;
        }
        float mx = lg[0];
        #pragma unroll
        for (int o = 1; o < CC; ++o) mx = fmaxf(mx, lg[o]);
        float se = 0.f;
        #pragma unroll
        for (int o = 0; o < CC; ++o) { lg[o] = expf(lg[o] - mx); se += lg[o]; }
        const float isum = 1.f / se;
        const size_t ob = obase + (size_t)rowsel * WW;
        #pragma unroll
        for (int c = 0; c < CC; ++c)
            out[ob + (size_t)c * (HH * WW)] = nrm[c] * lg[c] * isum;
    }
}

// ===========================================================================
// FALLBACK (round-1 path) — used only if ws_size is too small.
// ===========================================================================
#define HT_PITCH 68
__global__ __launch_bounds__(256) void mlp_fold_kernel_fb(
    const float* __restrict__ x,  const float* __restrict__ W1,
    const float* __restrict__ b1, const float* __restrict__ W2,
    const float* __restrict__ b2, float* __restrict__ folded)
{
    __shared__ __align__(16) float pT[PDIM * 64];
    __shared__ __align__(16) float hT[HIDN * HT_PITCH];
    const int tid = threadIdx.x;
    const int tile = blockIdx.x & 255;
    const int b = blockIdx.x >> 8;
    const int tile_base = tile * 64;
    const float* xb = x + (size_t)b * CC * HH * WW;
    for (int idx = tid; idx < PDIM * 64; idx += 256) {
        const int p = idx >> 6, lo = idx & 63;
        const int c = p / 9, rem = p - c * 9, i = rem / 3, j = rem - i * 3;
        const int l = tile_base + lo, a = l >> 7, bb = l & 127;
        int ym = 2 * a + i - 1, xm = 2 * bb + j - 1;
        if (ym < 0) ym = 1;
        if (xm < 0) xm = 1;
        pT[p * 64 + lo] = xb[(c * HH + ym) * WW + xm];
    }
    __syncthreads();
    {
        const int cg = tid & 31, rg = tid >> 5, rbase = rg * 8;
        float acc[8][4];
        #pragma unroll
        for (int m = 0; m < 8; ++m)
            #pragma unroll
            for (int jj = 0; jj < 4; ++jj) acc[m][jj] = 0.f;
        for (int k = 0; k < PDIM; ++k) {
            const float4 w = *reinterpret_cast<const float4*>(W1 + k * HIDN + cg * 4);
            const float4 pa = *reinterpret_cast<const float4*>(pT + k * 64 + rbase);
            const float4 pb2 = *reinterpret_cast<const float4*>(pT + k * 64 + rbase + 4);
            const float pv[8] = {pa.x, pa.y, pa.z, pa.w, pb2.x, pb2.y, pb2.z, pb2.w};
            const float wv[4] = {w.x, w.y, w.z, w.w};
            #pragma unroll
            for (int m = 0; m < 8; ++m)
                #pragma unroll
                for (int jj = 0; jj < 4; ++jj) acc[m][jj] = fmaf(pv[m], wv[jj], acc[m][jj]);
        }
        #pragma unroll
        for (int jj = 0; jj < 4; ++jj) {
            const int jcol = cg * 4 + jj;
            const float bj = b1[jcol];
            #pragma unroll
            for (int m = 0; m < 8; ++m) {
                const float hval = acc[m][jj] + bj;
                hT[jcol * HT_PITCH + rbase + m] = hval > 0.f ? hval : 0.f;
            }
        }
    }
    __syncthreads();
    {
        const int cg2 = tid & 15, rg2 = tid >> 4, rb2 = rg2 * 4;
        float acc2[4][9];
        #pragma unroll
        for (int m = 0; m < 4; ++m)
            #pragma unroll
            for (int jj = 0; jj < 9; ++jj) acc2[m][jj] = 0.f;
        const float* w2base = W2 + cg2 * 9;
        for (int h = 0; h < HIDN; ++h) {
            const float4 hv4 = *reinterpret_cast<const float4*>(hT + h * HT_PITCH + rb2);
            const float hv[4] = {hv4.x, hv4.y, hv4.z, hv4.w};
            float wv[9];
            #pragma unroll
            for (int jj = 0; jj < 9; ++jj) wv[jj] = w2base[h * PDIM + jj];
            #pragma unroll
            for (int m = 0; m < 4; ++m)
                #pragma unroll
                for (int jj = 0; jj < 9; ++jj) acc2[m][jj] = fmaf(hv[m], wv[jj], acc2[m][jj]);
        }
        float bv[9];
        #pragma unroll
        for (int jj = 0; jj < 9; ++jj) bv[jj] = b2[cg2 * 9 + jj];
        float* fb = folded + ((size_t)b * CC + cg2) * (HH * WW);
        #pragma unroll
        for (int m = 0; m < 4; ++m) {
            const int l = tile_base + rb2 + m, a = l >> 7, bb = l & 127;
            #pragma unroll
            for (int jj = 0; jj < 9; ++jj) {
                const int i = jj / 3, j2 = jj - i * 3;
                const int ypad = 2 * a + i, xpad = 2 * bb + j2;
                if (ypad >= 1 && xpad >= 1)
                    atomicAdd(fb + (ypad - 1) * WW + (xpad - 1), acc2[m][jj] + bv[jj]);
            }
        }
    }
}

__global__ __launch_bounds__(256) void norm_softmax_kernel_fb(
    float* __restrict__ out, const float* __restrict__ Wc, const float* __restrict__ bc)
{
    const int xo = threadIdx.x, yo = blockIdx.x & 255, b = blockIdx.x >> 8;
    const int yp = yo + 1, xp = xo + 1;
    const float cy = ((yp & 1) || yp == 256) ? 1.f : 2.f;
    const float cx = ((xp & 1) || xp == 256) ? 1.f : 2.f;
    const float inv = 1.f / (cy * cx + 1e-6f);
    const size_t base = ((size_t)b * CC) * (HH * WW) + (size_t)yo * WW + xo;
    float nrm[CC];
    #pragma unroll
    for (int c = 0; c < CC; ++c) nrm[c] = out[base + (size_t)c * (HH * WW)] * inv;
    float logits[CC];
    #pragma unroll
    for (int o = 0; o < CC; ++o) {
        float s = bc[o];
        #pragma unroll
        for (int c = 0; c < CC; ++c) s = fmaf(Wc[o * CC + c], nrm[c], s);
        logits[o] = s;
    }
    float mx = logits[0];
    #pragma unroll
    for (int o = 1; o < CC; ++o) mx = fmaxf(mx, logits[o]);
    float se = 0.f;
    #pragma unroll
    for (int o = 0; o < CC; ++o) { logits[o] = expf(logits[o] - mx); se += logits[o]; }
    const float isum = 1.f / se;
    #pragma unroll
    for (int c = 0; c < CC; ++c)
        out[base + (size_t)c * (HH * WW)] = nrm[c] * logits[c] * isum;
}

// ---------------------------------------------------------------------------
extern "C" void kernel_launch(void* const* d_in, const int* in_sizes, int n_in,
                              void* d_out, int out_size, void* d_ws, size_t ws_size,
                              hipStream_t stream)
{
    const float* x  = (const float*)d_in[0];
    const float* W1 = (const float*)d_in[1];
    const float* b1 = (const float*)d_in[2];
    const float* W2 = (const float*)d_in[3];
    const float* b2 = (const float*)d_in[4];
    const float* Wc = (const float*)d_in[5];
    const float* bc = (const float*)d_in[6];
    float* out = (float*)d_out;

    if (ws_size >= WS_NEEDED) {
        _Float16* og  = (_Float16*)d_ws;
        _Float16* W1T = (_Float16*)((char*)d_ws + W1T_OFF);
        _Float16* W2T = (_Float16*)((char*)d_ws + W2T_OFF);

        prep_kernel<<<dim3(80), dim3(256), 0, stream>>>(W1, W2, W1T, W2T);
        // 32 batches x 128 patch rows, 256 threads (4 waves)
        mlp_kernel<<<dim3(32 * 128), dim3(256), 0, stream>>>(x, W1T, b1, W2T, b2, og);
        // 32 batches x 128 row-pairs
        gather_kernel<<<dim3(32 * 128), dim3(256), 0, stream>>>(og, Wc, bc, out);
    } else {
        hipMemsetAsync(d_out, 0, (size_t)out_size * sizeof(float), stream);
        mlp_fold_kernel_fb<<<dim3(32 * 256), dim3(256), 0, stream>>>(x, W1, b1, W2, b2, out);
        norm_softmax_kernel_fb<<<dim3(32 * 256), dim3(256), 0, stream>>>(out, Wc, bc);
    }
}